// Round 23
// baseline (55.329 us; speedup 1.0000x reference)
//
#include <hip/hip_runtime.h>
#include <math.h>

typedef __fp16 h2 __attribute__((ext_vector_type(2)));
typedef float  f4 __attribute__((ext_vector_type(4)));   // native vec for nt-store

#define H_IN   136
#define W_IN   200
#define HWP    (H_IN * W_IN)       // 27200
#define OH     272
#define OW     400
#define RB     8                   // low-res rows per strip (17 strips)
#define NSTRIP 17
#define LROWS  (RB + 1)            // +1 halo row above
#define CH     8
#define CIN    8
#define NPARAM 169
#define NEG_LOG2E (-1.4426950408889634f)

// R23 = R22 (fp16 MLP, hoisted loads, nt stores) + phase-2 DIRECT-EMIT:
// the thread that computed low-res slot k keeps its 8 t-values in regs and
// emits output rows y1=2(r0+k)-1 (pure own row; skip k=0) and y2=2(r0+k)
// (avg own/next; skip k=8). Eliminates the separate 400-unit phase-2 pass
// (~10 LDS b128 reads + index math per 16px -> 3 small reads/thread).
// Vertical-then-horizontal lerp order preserved -> per-pixel math identical
// -> absmax canary 0.00390625.

__device__ __forceinline__ h2 pkrtz(float a, float b) {
    return __builtin_amdgcn_cvt_pkrtz(a, b);
}

__device__ __forceinline__ void nt_store4(float* p, float4 v) {
    f4 nv = {v.x, v.y, v.z, v.w};
    __builtin_nontemporal_store(nv, (f4*)p);
}

// Emit one output row of 16 px from 8 source values + left neighbor.
// out[2j] = 0.5*(s[j-1]+s[j]) (fx=0.5), out[2j+1] = s[j] (fx=0).
__device__ __forceinline__ void emit_row16(float* p, float left, const float* s) {
    float v[16];
    v[0] = 0.5f * (left + s[0]);
    #pragma unroll
    for (int j = 0; j < 8; ++j) {
        v[2 * j + 1] = s[j];
        if (j < 7) v[2 * j + 2] = 0.5f * (s[j] + s[j + 1]);
    }
    float4 a, b, c, d;
    a.x = __builtin_amdgcn_rcpf(1.0f + __builtin_amdgcn_exp2f(v[0]));
    a.y = __builtin_amdgcn_rcpf(1.0f + __builtin_amdgcn_exp2f(v[1]));
    a.z = __builtin_amdgcn_rcpf(1.0f + __builtin_amdgcn_exp2f(v[2]));
    a.w = __builtin_amdgcn_rcpf(1.0f + __builtin_amdgcn_exp2f(v[3]));
    b.x = __builtin_amdgcn_rcpf(1.0f + __builtin_amdgcn_exp2f(v[4]));
    b.y = __builtin_amdgcn_rcpf(1.0f + __builtin_amdgcn_exp2f(v[5]));
    b.z = __builtin_amdgcn_rcpf(1.0f + __builtin_amdgcn_exp2f(v[6]));
    b.w = __builtin_amdgcn_rcpf(1.0f + __builtin_amdgcn_exp2f(v[7]));
    c.x = __builtin_amdgcn_rcpf(1.0f + __builtin_amdgcn_exp2f(v[8]));
    c.y = __builtin_amdgcn_rcpf(1.0f + __builtin_amdgcn_exp2f(v[9]));
    c.z = __builtin_amdgcn_rcpf(1.0f + __builtin_amdgcn_exp2f(v[10]));
    c.w = __builtin_amdgcn_rcpf(1.0f + __builtin_amdgcn_exp2f(v[11]));
    d.x = __builtin_amdgcn_rcpf(1.0f + __builtin_amdgcn_exp2f(v[12]));
    d.y = __builtin_amdgcn_rcpf(1.0f + __builtin_amdgcn_exp2f(v[13]));
    d.z = __builtin_amdgcn_rcpf(1.0f + __builtin_amdgcn_exp2f(v[14]));
    d.w = __builtin_amdgcn_rcpf(1.0f + __builtin_amdgcn_exp2f(v[15]));
    nt_store4(p,      a);
    nt_store4(p + 4,  b);
    nt_store4(p + 8,  c);
    nt_store4(p + 12, d);
}

__global__ __launch_bounds__(256, 3) void mask_head_fused(
    const float* __restrict__ mask_feats,   // (N, 8, H, W)
    const float* __restrict__ params,       // (n_inst, 169)
    const float* __restrict__ locations,    // (n_inst, 2)
    const int*   __restrict__ im_inds,      // (n_inst,)
    const int*   __restrict__ fpn_levels,   // (n_inst,)
    const float* __restrict__ soi_tab,      // (5,)
    float* __restrict__ out)                // (n_inst, 272, 400)
{
    __shared__ h2    sW[NPARAM];            // packed (dup) fp16 weights
    __shared__ float T[LROWS][W_IN];        // t = -log2e * logit

    const int inst = blockIdx.y;
    const int r0   = blockIdx.x * RB;
    const int tid  = threadIdx.x;

    const float* F = mask_feats + (size_t)im_inds[inst] * (CIN * HWP);

    // ---- feature loads issued FIRST (depend only on tid/blockIdx) ----
    const int  k_u = tid / 25;
    const int  c_u = (tid - k_u * 25) * 8;
    const int  r_u = min(max(r0 - 1 + k_u, 0), H_IN - 1);
    const bool p1  = (tid < LROWS * 25);

    float4 fA[CIN], fB[CIN];
    if (p1) {
        #pragma unroll
        for (int ch = 0; ch < CIN; ++ch) {
            const float* q = F + ch * HWP + r_u * W_IN + c_u;
            fA[ch] = *(const float4*)q;
            fB[ch] = *(const float4*)(q + 4);
        }
    }

    // ---- weight staging overlaps the in-flight loads ----
    const float* P = params + inst * NPARAM;
    if (tid < NPARAM) {
        float w = P[tid];
        if ((tid >= 144 && tid < 152) || tid == 168) w *= NEG_LOG2E;
        const __fp16 hw = (__fp16)w;
        h2 v; v.x = hw; v.y = hw;
        sW[tid] = v;
    }

    const float loc_x   = locations[2 * inst];
    const float loc_y   = locations[2 * inst + 1];
    const float inv_soi = 1.0f / soi_tab[fpn_levels[inst]];
    float* O = out + (size_t)inst * (OH * OW);
    __syncthreads();

    // ---- Phase 1: 225 units of 8 px, packed fp16 MLP; tf kept in regs ----
    float tf[8];
    if (p1) {
        h2 f[CIN][4];
        #pragma unroll
        for (int ch = 0; ch < CIN; ++ch) {
            f[ch][0] = pkrtz(fA[ch].x, fA[ch].y); f[ch][1] = pkrtz(fA[ch].z, fA[ch].w);
            f[ch][2] = pkrtz(fB[ch].x, fB[ch].y); f[ch][3] = pkrtz(fB[ch].z, fB[ch].w);
        }

        const float ry  = (loc_y - (float)(r_u * 8 + 4)) * inv_soi;
        const float dx  = -8.0f * inv_soi;
        const float rx0 = (loc_x - (float)(c_u * 8 + 4)) * inv_soi;
        h2 rxh[4];
        #pragma unroll
        for (int s = 0; s < 4; ++s)
            rxh[s] = pkrtz(rx0 + (float)(2 * s) * dx, rx0 + (float)(2 * s + 1) * dx);
        const h2 ryh = pkrtz(ry, ry);
        const h2 z2  = {(__fp16)0.0f, (__fp16)0.0f};

        h2 h0[CH][4];
        #pragma unroll
        for (int o = 0; o < CH; ++o) {
            const h2 base = __builtin_elementwise_fma(sW[o * 10 + 1], ryh, sW[152 + o]);
            const h2 wx = sW[o * 10];
            h2 a[4];
            #pragma unroll
            for (int s = 0; s < 4; ++s) a[s] = __builtin_elementwise_fma(wx, rxh[s], base);
            #pragma unroll
            for (int i = 0; i < CIN; ++i) {
                const h2 w = sW[o * 10 + 2 + i];
                #pragma unroll
                for (int s = 0; s < 4; ++s) a[s] = __builtin_elementwise_fma(w, f[i][s], a[s]);
            }
            #pragma unroll
            for (int s = 0; s < 4; ++s) h0[o][s] = __builtin_elementwise_max(a[s], z2);
        }

        h2 h1[CH][4];
        #pragma unroll
        for (int o = 0; o < CH; ++o) {
            const h2 b = sW[160 + o];
            h2 a[4] = {b, b, b, b};
            #pragma unroll
            for (int i = 0; i < CH; ++i) {
                const h2 w = sW[80 + o * CH + i];
                #pragma unroll
                for (int s = 0; s < 4; ++s) a[s] = __builtin_elementwise_fma(w, h0[i][s], a[s]);
            }
            #pragma unroll
            for (int s = 0; s < 4; ++s) h1[o][s] = __builtin_elementwise_max(a[s], z2);
        }

        const h2 b2 = sW[168];
        h2 t[4] = {b2, b2, b2, b2};
        #pragma unroll
        for (int i = 0; i < CH; ++i) {
            const h2 w = sW[144 + i];
            #pragma unroll
            for (int s = 0; s < 4; ++s) t[s] = __builtin_elementwise_fma(w, h1[i][s], t[s]);
        }

        #pragma unroll
        for (int s = 0; s < 4; ++s) {
            tf[2 * s]     = (float)t[s].x;
            tf[2 * s + 1] = (float)t[s].y;
        }
        *(float4*)&T[k_u][c_u]     = make_float4(tf[0], tf[1], tf[2], tf[3]);
        *(float4*)&T[k_u][c_u + 4] = make_float4(tf[4], tf[5], tf[6], tf[7]);
    }
    __syncthreads();

    // ---- Phase 2: direct-emit from registers ----
    // Thread (k,c) emits y1 = 2(r0+k)-1 (pure own row; k>0) and
    // y2 = 2(r0+k) (avg own/next; k<8), 16 px wide at x0 = 2c.
    if (p1) {
        const int cl = max(c_u - 1, 0);
        const int kn = min(k_u + 1, LROWS - 1);      // k=8's next unused
        const float ol = T[k_u][cl];                 // own-row left neighbor

        if (k_u > 0) {
            const int y1 = 2 * (r0 + k_u) - 1;
            emit_row16(O + (size_t)y1 * OW + 2 * c_u, ol, tf);
        }
        if (k_u < LROWS - 1) {
            const float4 n0 = *(const float4*)&T[kn][c_u];
            const float4 n1 = *(const float4*)&T[kn][c_u + 4];
            const float  nl = T[kn][cl];
            float s[8];
            s[0] = 0.5f * (tf[0] + n0.x); s[1] = 0.5f * (tf[1] + n0.y);
            s[2] = 0.5f * (tf[2] + n0.z); s[3] = 0.5f * (tf[3] + n0.w);
            s[4] = 0.5f * (tf[4] + n1.x); s[5] = 0.5f * (tf[5] + n1.y);
            s[6] = 0.5f * (tf[6] + n1.z); s[7] = 0.5f * (tf[7] + n1.w);
            const float sl = 0.5f * (ol + nl);
            const int y2 = 2 * (r0 + k_u);
            emit_row16(O + (size_t)y2 * OW + 2 * c_u, sl, s);
        }
    }
}

extern "C" void kernel_launch(void* const* d_in, const int* in_sizes, int n_in,
                              void* d_out, int out_size, void* d_ws, size_t ws_size,
                              hipStream_t stream) {
    const float* mask_feats = (const float*)d_in[0];
    const float* params     = (const float*)d_in[1];
    const float* locations  = (const float*)d_in[2];
    const int*   im_inds    = (const int*)d_in[3];
    const int*   fpn_levels = (const int*)d_in[4];
    const float* soi_tab    = (const float*)d_in[5];

    const int n_inst = in_sizes[1] / NPARAM;   // 128
    dim3 grid(NSTRIP, n_inst);                 // (17, 128)
    mask_head_fused<<<grid, 256, 0, stream>>>(
        mask_feats, params, locations, im_inds, fpn_levels, soi_tab, (float*)d_out);
}

// Round 24
// 24.179 us; speedup vs baseline: 2.2883x; 2.2883x over previous
//
#include <hip/hip_runtime.h>
#include <math.h>

typedef __fp16 h2 __attribute__((ext_vector_type(2)));
typedef float  f4 __attribute__((ext_vector_type(4)));   // native vec for nt-store

#define H_IN   136
#define W_IN   200
#define HWP    (H_IN * W_IN)       // 27200
#define OH     272
#define OW     400
#define RB     8                   // low-res rows per strip (17 strips)
#define NSTRIP 17
#define LROWS  (RB + 1)            // +1 halo row above
#define CH     8
#define CIN    8
#define NPARAM 169
#define NEG_LOG2E (-1.4426950408889634f)

// R24 = revert to R22/R19 (best verified: 24.14us). R23's direct-emit
// doubled WRITE_SIZE (113.5MB vs 54.4MB): nt-stores bypass L2, so the
// 16B-fragment/64B-stride lane pattern couldn't merge into full lines ->
// RMW amplification. Rule logged: with nt-stores, per-instruction wave
// coalescing is mandatory (consecutive lanes -> consecutive float4s).
// Levers retained: fp16 MLP, hoisted feature loads, nt stores (coalesced).
// absmax canary 0.00390625.

__device__ __forceinline__ h2 pkrtz(float a, float b) {
    return __builtin_amdgcn_cvt_pkrtz(a, b);
}

__device__ __forceinline__ void nt_store4(float* p, float4 v) {
    f4 nv = {v.x, v.y, v.z, v.w};
    __builtin_nontemporal_store(nv, (f4*)p);
}

__global__ __launch_bounds__(256, 3) void mask_head_fused(
    const float* __restrict__ mask_feats,   // (N, 8, H, W)
    const float* __restrict__ params,       // (n_inst, 169)
    const float* __restrict__ locations,    // (n_inst, 2)
    const int*   __restrict__ im_inds,      // (n_inst,)
    const int*   __restrict__ fpn_levels,   // (n_inst,)
    const float* __restrict__ soi_tab,      // (5,)
    float* __restrict__ out)                // (n_inst, 272, 400)
{
    __shared__ h2    sW[NPARAM];            // packed (dup) fp16 weights
    __shared__ float T[LROWS][W_IN];        // t = -log2e * logit

    const int inst = blockIdx.y;
    const int r0   = blockIdx.x * RB;
    const int tid  = threadIdx.x;

    const float* F = mask_feats + (size_t)im_inds[inst] * (CIN * HWP);

    // ---- feature loads issued FIRST (depend only on tid/blockIdx) ----
    const int  k_u = tid / 25;
    const int  c_u = (tid - k_u * 25) * 8;
    const int  r_u = min(max(r0 - 1 + k_u, 0), H_IN - 1);
    const bool p1  = (tid < LROWS * 25);

    float4 fA[CIN], fB[CIN];
    if (p1) {
        #pragma unroll
        for (int ch = 0; ch < CIN; ++ch) {
            const float* q = F + ch * HWP + r_u * W_IN + c_u;
            fA[ch] = *(const float4*)q;
            fB[ch] = *(const float4*)(q + 4);
        }
    }

    // ---- weight staging overlaps the in-flight loads ----
    const float* P = params + inst * NPARAM;
    if (tid < NPARAM) {
        float w = P[tid];
        if ((tid >= 144 && tid < 152) || tid == 168) w *= NEG_LOG2E;
        const __fp16 hw = (__fp16)w;
        h2 v; v.x = hw; v.y = hw;
        sW[tid] = v;
    }

    const float loc_x   = locations[2 * inst];
    const float loc_y   = locations[2 * inst + 1];
    const float inv_soi = 1.0f / soi_tab[fpn_levels[inst]];
    float* O = out + (size_t)inst * (OH * OW);
    __syncthreads();

    // ---- Phase 1: 225 units of 8 px (4 half2 slots), packed fp16 MLP ----
    if (p1) {
        h2 f[CIN][4];
        #pragma unroll
        for (int ch = 0; ch < CIN; ++ch) {
            f[ch][0] = pkrtz(fA[ch].x, fA[ch].y); f[ch][1] = pkrtz(fA[ch].z, fA[ch].w);
            f[ch][2] = pkrtz(fB[ch].x, fB[ch].y); f[ch][3] = pkrtz(fB[ch].z, fB[ch].w);
        }

        const float ry  = (loc_y - (float)(r_u * 8 + 4)) * inv_soi;
        const float dx  = -8.0f * inv_soi;
        const float rx0 = (loc_x - (float)(c_u * 8 + 4)) * inv_soi;
        h2 rxh[4];
        #pragma unroll
        for (int s = 0; s < 4; ++s)
            rxh[s] = pkrtz(rx0 + (float)(2 * s) * dx, rx0 + (float)(2 * s + 1) * dx);
        const h2 ryh = pkrtz(ry, ry);
        const h2 z2  = {(__fp16)0.0f, (__fp16)0.0f};

        h2 h0[CH][4];
        #pragma unroll
        for (int o = 0; o < CH; ++o) {
            const h2 base = __builtin_elementwise_fma(sW[o * 10 + 1], ryh, sW[152 + o]);
            const h2 wx = sW[o * 10];
            h2 a[4];
            #pragma unroll
            for (int s = 0; s < 4; ++s) a[s] = __builtin_elementwise_fma(wx, rxh[s], base);
            #pragma unroll
            for (int i = 0; i < CIN; ++i) {
                const h2 w = sW[o * 10 + 2 + i];
                #pragma unroll
                for (int s = 0; s < 4; ++s) a[s] = __builtin_elementwise_fma(w, f[i][s], a[s]);
            }
            #pragma unroll
            for (int s = 0; s < 4; ++s) h0[o][s] = __builtin_elementwise_max(a[s], z2);
        }

        h2 h1[CH][4];
        #pragma unroll
        for (int o = 0; o < CH; ++o) {
            const h2 b = sW[160 + o];
            h2 a[4] = {b, b, b, b};
            #pragma unroll
            for (int i = 0; i < CH; ++i) {
                const h2 w = sW[80 + o * CH + i];
                #pragma unroll
                for (int s = 0; s < 4; ++s) a[s] = __builtin_elementwise_fma(w, h0[i][s], a[s]);
            }
            #pragma unroll
            for (int s = 0; s < 4; ++s) h1[o][s] = __builtin_elementwise_max(a[s], z2);
        }

        const h2 b2 = sW[168];
        h2 t[4] = {b2, b2, b2, b2};
        #pragma unroll
        for (int i = 0; i < CH; ++i) {
            const h2 w = sW[144 + i];
            #pragma unroll
            for (int s = 0; s < 4; ++s) t[s] = __builtin_elementwise_fma(w, h1[i][s], t[s]);
        }

        *(float4*)&T[k_u][c_u] = make_float4((float)t[0].x, (float)t[0].y,
                                             (float)t[1].x, (float)t[1].y);
        *(float4*)&T[k_u][c_u + 4] = make_float4((float)t[2].x, (float)t[2].y,
                                                 (float)t[3].x, (float)t[3].y);
    }
    __syncthreads();

    // ---- Phase 2: 400 units of 16 px (8 wide x 2 output rows), nt stores ----
    #pragma unroll
    for (int it = 0; it < 2; ++it) {
        const int s = tid + 256 * it;
        if (s < RB * (W_IN / 4)) {
            const int rpl = s / (W_IN / 4);         // 0..7
            const int t   = s - rpl * (W_IN / 4);   // 0..49
            const int cm  = 4 * t;
            const int cl  = max(cm - 1, 0);

            const float4 mR = *(const float4*)&T[rpl + 1][cm];
            const float4 mQ = *(const float4*)&T[rpl][cm];
            const float  AR = T[rpl + 1][cl];       // == mR.x when t==0
            const float  AQ = T[rpl][cl];

            const float Aa = 0.5f * (AR + AQ);
            const float Ba = 0.5f * (mR.x + mQ.x);
            const float Ca = 0.5f * (mR.y + mQ.y);
            const float Da = 0.5f * (mR.z + mQ.z);
            const float Ea = 0.5f * (mR.w + mQ.w);

            float4 s0, s1, s2, s3;
            s0.x = __builtin_amdgcn_rcpf(1.0f + __builtin_amdgcn_exp2f(0.5f * (Aa + Ba)));
            s0.y = __builtin_amdgcn_rcpf(1.0f + __builtin_amdgcn_exp2f(Ba));
            s0.z = __builtin_amdgcn_rcpf(1.0f + __builtin_amdgcn_exp2f(0.5f * (Ba + Ca)));
            s0.w = __builtin_amdgcn_rcpf(1.0f + __builtin_amdgcn_exp2f(Ca));
            s1.x = __builtin_amdgcn_rcpf(1.0f + __builtin_amdgcn_exp2f(0.5f * (Ca + Da)));
            s1.y = __builtin_amdgcn_rcpf(1.0f + __builtin_amdgcn_exp2f(Da));
            s1.z = __builtin_amdgcn_rcpf(1.0f + __builtin_amdgcn_exp2f(0.5f * (Da + Ea)));
            s1.w = __builtin_amdgcn_rcpf(1.0f + __builtin_amdgcn_exp2f(Ea));

            s2.x = __builtin_amdgcn_rcpf(1.0f + __builtin_amdgcn_exp2f(0.5f * (AR + mR.x)));
            s2.y = __builtin_amdgcn_rcpf(1.0f + __builtin_amdgcn_exp2f(mR.x));
            s2.z = __builtin_amdgcn_rcpf(1.0f + __builtin_amdgcn_exp2f(0.5f * (mR.x + mR.y)));
            s2.w = __builtin_amdgcn_rcpf(1.0f + __builtin_amdgcn_exp2f(mR.y));
            s3.x = __builtin_amdgcn_rcpf(1.0f + __builtin_amdgcn_exp2f(0.5f * (mR.y + mR.z)));
            s3.y = __builtin_amdgcn_rcpf(1.0f + __builtin_amdgcn_exp2f(mR.z));
            s3.z = __builtin_amdgcn_rcpf(1.0f + __builtin_amdgcn_exp2f(0.5f * (mR.z + mR.w)));
            s3.w = __builtin_amdgcn_rcpf(1.0f + __builtin_amdgcn_exp2f(mR.w));

            float* O0 = O + (size_t)(2 * (r0 + rpl)) * OW + 8 * t;
            nt_store4(O0,          s0);
            nt_store4(O0 + 4,      s1);
            nt_store4(O0 + OW,     s2);
            nt_store4(O0 + OW + 4, s3);
        }
    }
}

extern "C" void kernel_launch(void* const* d_in, const int* in_sizes, int n_in,
                              void* d_out, int out_size, void* d_ws, size_t ws_size,
                              hipStream_t stream) {
    const float* mask_feats = (const float*)d_in[0];
    const float* params     = (const float*)d_in[1];
    const float* locations  = (const float*)d_in[2];
    const int*   im_inds    = (const int*)d_in[3];
    const int*   fpn_levels = (const int*)d_in[4];
    const float* soi_tab    = (const float*)d_in[5];

    const int n_inst = in_sizes[1] / NPARAM;   // 128
    dim3 grid(NSTRIP, n_inst);                 // (17, 128)
    mask_head_fused<<<grid, 256, 0, stream>>>(
        mask_feats, params, locations, im_inds, fpn_levels, soi_tab, (float*)d_out);
}